// Round 9
// baseline (500.083 us; speedup 1.0000x reference)
//
#include <hip/hip_runtime.h>

static constexpr int T_LEN = 1024;

typedef _Float16 f16;
typedef f16  f16x4 __attribute__((ext_vector_type(4)));
typedef float f32x4 __attribute__((ext_vector_type(4)));

__device__ __forceinline__ f32x4 mfma16(f16x4 a, f16x4 b, f32x4 c) {
    return __builtin_amdgcn_mfma_f32_16x16x16f16(a, b, c, 0, 0, 0);
}
// 1/(1+2^t): overflow-safe (t->+inf: exp2=inf, rcp->0; t->-inf: ->1)
__device__ __forceinline__ float sig2(float t) {
    return __builtin_amdgcn_rcpf(1.f + __builtin_amdgcn_exp2f(t));
}

// 8 waves per block (512 thr), 16 sequences per block, 256 blocks:
// 8 waves/CU = 2 per SIMD. Wave w = lyr*4+g owns layer lyr's gate g
// (PyTorch i,f,g,o): phase A = 1 MFMA + 4 sig2 (was 2 MFMA + 8 sig2 at 4
// waves), written to double-buffered LDS, ONE barrier per step (write slot
// t&1; reuse at t+2 is ordered through the t+1 barrier by program order).
// Phase B: L1 waves read the 4 L1 tiles and update c1/h1f; L2 waves read
// all 8, update c1/h1f and c2/h2f, then refresh pre2 = Whh1*h2+b2.
// The 2nd wave per SIMD hides MFMA/LDS/barrier latency.
// Fragments (v_mfma_f32_16x16x16f16):
//   A[m][k]: lane = m + 16*(k/4), reg = k%4   (weights, f16, pre-scaled)
//   B[k][n]: lane = n + 16*(k/4), reg = k%4   (H^T: k=hidden, n=seq)
//   D[m][n]: lane = n + 16*(m/4), reg = m%4   (gates)
// D and B share the lane mapping, so updated h feeds the next MFMA directly.
// Layer 2 runs ONE STEP DELAYED: iteration t computes L1 step t and L2 step
// t-1 from h1[t-1], h2[t-2]; pre2 is refreshed right after each h2 update.
__global__ void __launch_bounds__(512, 1) lstm2_8w_kernel(
    const float* __restrict__ x,
    const float* __restrict__ Wih0, const float* __restrict__ Whh0,
    const float* __restrict__ bih0, const float* __restrict__ bhh0,
    const float* __restrict__ Wih1, const float* __restrict__ Whh1,
    const float* __restrict__ bih1, const float* __restrict__ bhh1,
    const float* __restrict__ Wout, const float* __restrict__ bout,
    float* __restrict__ out)
{
    const int tid = threadIdx.x;
    const int w8  = tid >> 6;          // wave id: lyr*4 + g
    const int lyr = w8 >> 2;
    const int g   = w8 & 3;
    const int l   = tid & 63;
    const int col = l & 15;            // seq within tile; A within-block row
    const int q   = l >> 4;
    const int seq = blockIdx.x * 16 + col;

    // [slot][layer][gate][lane*4]: 16 KB, per-lane 16B contiguous.
    __shared__ __align__(16) float smem[2][2][4][256];

    const float L2E = 1.442695041f;
    const float NT  = -2.f * L2E;      // tanh(c) scale
    const float ns  = (g == 2) ? (-2.f * L2E) : (-L2E);  // gate pre-scale

    // ---- this wave's constant fragments (f16 weights, pre-scaled).
    f16x4 WaA = {}, WaB = {};          // L1: Whh0 ; L2: Wih1, Whh1
    f32x4 cbD = {}, wxD = {};          // L1: bias1, Wih0 ; L2: bias2
    {
        const int arow = g * 16 + col;
        if (lyr == 0) {
#pragma unroll
            for (int r = 0; r < 4; ++r) {
                WaA[r] = (f16)(ns * Whh0[arow * 16 + q * 4 + r]);
                const int drow = g * 16 + q * 4 + r;
                cbD[r] = ns * (bih0[drow] + bhh0[drow]);
                wxD[r] = ns * Wih0[drow];
            }
        } else {
#pragma unroll
            for (int r = 0; r < 4; ++r) {
                WaA[r] = (f16)(ns * Wih1[arow * 16 + q * 4 + r]);
                WaB[r] = (f16)(ns * Whh1[arow * 16 + q * 4 + r]);
                const int drow = g * 16 + q * 4 + r;
                cbD[r] = ns * (bih1[drow] + bhh1[drow]);
            }
        }
    }
    asm volatile("" : "+v"(WaA), "+v"(WaB), "+v"(cbD), "+v"(wxD));

    f16x4 h1f = {}, h2f = {};          // h1[t-1], h2[t-2] (B layout, f16)
    f32x4 c1 = {0.f, 0.f, 0.f, 0.f}, c2 = {0.f, 0.f, 0.f, 0.f};
    f32x4 h2v = {0.f, 0.f, 0.f, 0.f};
    f32x4 pre2 = cbD;                  // L2: Whh1·h2[t-2] + b2 (h2[-1]=0)

    const float* xb = x + (size_t)seq * T_LEN;
    float4 xq = make_float4(0.f, 0.f, 0.f, 0.f);
    if (lyr == 0) xq = *reinterpret_cast<const float4*>(xb);

    for (int tb = 0; tb < T_LEN; tb += 4) {
        float4 xn = xq;
        if (lyr == 0 && tb + 4 < T_LEN)
            xn = *reinterpret_cast<const float4*>(xb + tb + 4);
#pragma unroll
        for (int u = 0; u < 4; ++u) {
            const int   t    = tb + u;
            const int   slot = u & 1;          // == t&1
            const float xv   = (u==0)?xq.x:(u==1)?xq.y:(u==2)?xq.z:xq.w;

            // ---- phase A: this wave's gate tile, activated, into LDS.
            f32x4 s;
            if (lyr == 0) {                    // L1 step t
                f32x4 ci;
#pragma unroll
                for (int r = 0; r < 4; ++r)
                    ci[r] = fmaf(wxD[r], xv, cbD[r]);
                const f32x4 d = mfma16(WaA, h1f, ci);
#pragma unroll
                for (int r = 0; r < 4; ++r) s[r] = sig2(d[r]);
            } else {                           // L2 step t-1
                const f32x4 d = mfma16(WaA, h1f, pre2);
#pragma unroll
                for (int r = 0; r < 4; ++r) s[r] = sig2(d[r]);
            }
            if (g == 2) {
#pragma unroll
                for (int r = 0; r < 4; ++r) s[r] = fmaf(2.f, s[r], -1.f);
            }
            *reinterpret_cast<f32x4*>(&smem[slot][lyr][g][l * 4]) = s;
            __syncthreads();

            // ---- phase B: read gate tiles, update state.
            const f32x4 A0 = *reinterpret_cast<const f32x4*>(&smem[slot][0][0][l * 4]);
            const f32x4 A1 = *reinterpret_cast<const f32x4*>(&smem[slot][0][1][l * 4]);
            const f32x4 A2 = *reinterpret_cast<const f32x4*>(&smem[slot][0][2][l * 4]);
            const f32x4 A3 = *reinterpret_cast<const f32x4*>(&smem[slot][0][3][l * 4]);

            if (lyr == 1 && t >= 1) {          // L2 step t-1 update
                const f32x4 B0 = *reinterpret_cast<const f32x4*>(&smem[slot][1][0][l * 4]);
                const f32x4 B1 = *reinterpret_cast<const f32x4*>(&smem[slot][1][1][l * 4]);
                const f32x4 B2 = *reinterpret_cast<const f32x4*>(&smem[slot][1][2][l * 4]);
                const f32x4 B3 = *reinterpret_cast<const f32x4*>(&smem[slot][1][3][l * 4]);
#pragma unroll
                for (int r = 0; r < 4; ++r) {
                    c2[r] = fmaf(B1[r], c2[r], B0[r] * B2[r]);
                    const float th = fmaf(2.f, sig2(NT * c2[r]), -1.f);
                    h2v[r] = B3[r] * th;
                    h2f[r] = (f16)h2v[r];
                }
                pre2 = mfma16(WaB, h2f, cbD);
            }
#pragma unroll
            for (int r = 0; r < 4; ++r) {      // L1 step t update (all waves)
                c1[r] = fmaf(A1[r], c1[r], A0[r] * A2[r]);
                const float th = fmaf(2.f, sig2(NT * c1[r]), -1.f);
                h1f[r] = (f16)(A3[r] * th);
            }
        }
        xq = xn;
    }

    // ---- epilogue: L2 step T-1 (h1f = h1[T-1], pre2 = Whh1·h2[T-2]+b2)
    if (lyr == 1) {
        const f32x4 d = mfma16(WaA, h1f, pre2);
        f32x4 s;
#pragma unroll
        for (int r = 0; r < 4; ++r) s[r] = sig2(d[r]);
        if (g == 2) {
#pragma unroll
            for (int r = 0; r < 4; ++r) s[r] = fmaf(2.f, s[r], -1.f);
        }
        *reinterpret_cast<f32x4*>(&smem[0][1][g][l * 4]) = s;
    }
    __syncthreads();

    // ---- head (wave 4 only): out[seq][m] = relu(h2) . Wout[m] + bout[m]
    if (w8 == 4) {
        const f32x4 B0 = *reinterpret_cast<const f32x4*>(&smem[0][1][0][l * 4]);
        const f32x4 B1 = *reinterpret_cast<const f32x4*>(&smem[0][1][1][l * 4]);
        const f32x4 B2 = *reinterpret_cast<const f32x4*>(&smem[0][1][2][l * 4]);
        const f32x4 B3 = *reinterpret_cast<const f32x4*>(&smem[0][1][3][l * 4]);
#pragma unroll
        for (int r = 0; r < 4; ++r) {
            c2[r] = fmaf(B1[r], c2[r], B0[r] * B2[r]);
            const float th = fmaf(2.f, sig2(NT * c2[r]), -1.f);
            h2v[r] = B3[r] * th;
        }
#pragma unroll
        for (int m = 0; m < 5; ++m) {
            float p = 0.f;
#pragma unroll
            for (int r = 0; r < 4; ++r)
                p = fmaf(fmaxf(h2v[r], 0.f), Wout[m * 16 + q * 4 + r], p);
            p += __shfl_xor(p, 16, 64);
            p += __shfl_xor(p, 32, 64);
            if (q == 0) out[seq * 5 + m] = p + bout[m];
        }
    }
}

extern "C" void kernel_launch(void* const* d_in, const int* in_sizes, int n_in,
                              void* d_out, int out_size, void* d_ws, size_t ws_size,
                              hipStream_t stream) {
    const float* x    = (const float*)d_in[0];
    const float* Wih0 = (const float*)d_in[1];
    const float* Whh0 = (const float*)d_in[2];
    const float* bih0 = (const float*)d_in[3];
    const float* bhh0 = (const float*)d_in[4];
    const float* Wih1 = (const float*)d_in[5];
    const float* Whh1 = (const float*)d_in[6];
    const float* bih1 = (const float*)d_in[7];
    const float* bhh1 = (const float*)d_in[8];
    const float* Wout = (const float*)d_in[9];
    const float* bout = (const float*)d_in[10];
    float* out = (float*)d_out;

    const int B = in_sizes[0] / T_LEN;          // 4096
    dim3 grid(B / 16), block(512);              // 8 waves / 16 seqs per block
    hipLaunchKernelGGL(lstm2_8w_kernel, grid, block, 0, stream,
                       x, Wih0, Whh0, bih0, bhh0,
                       Wih1, Whh1, bih1, bhh1, Wout, bout, out);
}

// Round 10
// 254.472 us; speedup vs baseline: 1.9652x; 1.9652x over previous
//
#include <hip/hip_runtime.h>

static constexpr int T_LEN = 1024;

typedef _Float16 f16;
typedef f16  f16x4 __attribute__((ext_vector_type(4)));
typedef float f32x4 __attribute__((ext_vector_type(4)));

__device__ __forceinline__ f32x4 mfma16(f16x4 a, f16x4 b, f32x4 c) {
    return __builtin_amdgcn_mfma_f32_16x16x16f16(a, b, c, 0, 0, 0);
}
// 1/(1+2^t): overflow-safe (t->+inf: exp2=inf, rcp->0; t->-inf: ->1)
__device__ __forceinline__ float sig2(float t) {
    return __builtin_amdgcn_rcpf(1.f + __builtin_amdgcn_exp2f(t));
}

// 8 waves (512 thr) per block, 16 seqs per block, 256 blocks = 2 waves/SIMD.
// Wave w8 = lyr*4+q owns layer lyr, unit-block q (units 4q..4q+3).
//
// ROW-INTERLEAVED A-fragments: tile-row m = gate(m&3) of unit(4q + (m>>2)),
// i.e. weight row (m&3)*16 + 4q + (m>>2). With the D-layout
// (row = 4*(lane>>4)+reg), each lane's f32x4 D = (i,f,g,o) of ONE unit
// (u1 = 4q + (lane>>4)) for its seq (lane&15): the LSTM update is fully
// lane-local; the tanh gate is compile-time element 2. Only h itself is
// exchanged: 1 f16 scalar write + 1 ds_read_b64 per wave per step, through
// double-buffered LDS (slot t&1; reuse at t+2 ordered by the t+1 barrier),
// ONE barrier per step.
// Layer 2 runs ONE STEP DELAYED: iter t computes L1 step t and L2 step t-1
// from h1[t-1], h2[t-2]; pre2 = Whh1·h2 + b2 refreshed post-barrier.
__global__ void __launch_bounds__(512, 1) lstm2_unit_kernel(
    const float* __restrict__ x,
    const float* __restrict__ Wih0, const float* __restrict__ Whh0,
    const float* __restrict__ bih0, const float* __restrict__ bhh0,
    const float* __restrict__ Wih1, const float* __restrict__ Whh1,
    const float* __restrict__ bih1, const float* __restrict__ bhh1,
    const float* __restrict__ Wout, const float* __restrict__ bout,
    float* __restrict__ out)
{
    const int tid = threadIdx.x;
    const int w8  = tid >> 6;          // lyr*4 + q
    const int lyr = w8 >> 2;
    const int q   = w8 & 3;
    const int l   = tid & 63;
    const int n   = l & 15;            // seq col (B/D); A tile-row
    const int Lq  = l >> 4;            // lane quad
    const int seq = blockIdx.x * 16 + n;

    // h exchange: [slot][layer][seq][unit(+pad)] f16; head area f32.
    __shared__ __align__(16) f16   hx[2][2][16][20];
    __shared__ __align__(16) float h2fin[16][20];

    const float L2E = 1.442695041f;
    const float NT  = -2.f * L2E;      // tanh(c) scale

    // A rows (tile-row m = lane&15): gate m&3, unit 4q + (m>>2).
    const int   gA    = n & 3;
    const int   wrowA = gA * 16 + 4 * q + (n >> 2);
    const float nsA   = (gA == 2) ? (-2.f * L2E) : (-L2E);
    // D rows (reg r): gate r, unit u1 = 4q + Lq.
    const int   u1    = 4 * q + Lq;

    f16x4 WaA = {}, WaB = {};          // L1: Whh0 ; L2: Wih1, Whh1
    f32x4 cbD, wxD = {};               // D-layout: bias, Wih0 (L1 only)
#pragma unroll
    for (int r = 0; r < 4; ++r) {
        const float nsD  = (r == 2) ? (-2.f * L2E) : (-L2E);
        const int   wrdD = r * 16 + u1;
        if (lyr == 0) {
            WaA[r] = (f16)(nsA * Whh0[wrowA * 16 + 4 * Lq + r]);
            cbD[r] = nsD * (bih0[wrdD] + bhh0[wrdD]);
            wxD[r] = nsD * Wih0[wrdD];
        } else {
            WaA[r] = (f16)(nsA * Wih1[wrowA * 16 + 4 * Lq + r]);
            WaB[r] = (f16)(nsA * Whh1[wrowA * 16 + 4 * Lq + r]);
            cbD[r] = nsD * (bih1[wrdD] + bhh1[wrdD]);
        }
    }
    asm volatile("" : "+v"(WaA), "+v"(WaB), "+v"(cbD), "+v"(wxD));

    f16x4 h1f = {}, h2f = {};          // full h1[t-1], h2[t-1] (B layout)
    float c1 = 0.f, c2 = 0.f;          // this lane's unit state
    f32x4 pre2 = cbD;                  // L2: Whh1·h2[t-2] + b2 (h2[-1]=0)

    const float* xb = x + (size_t)seq * T_LEN;
    float4 xq = make_float4(0.f, 0.f, 0.f, 0.f);
    if (lyr == 0) xq = *reinterpret_cast<const float4*>(xb);

    for (int tb = 0; tb < T_LEN; tb += 4) {
        float4 xn = xq;
        if (lyr == 0 && tb + 4 < T_LEN)
            xn = *reinterpret_cast<const float4*>(xb + tb + 4);
#pragma unroll
        for (int u = 0; u < 4; ++u) {
            const int   t    = tb + u;
            const int   slot = u & 1;          // == t&1
            const float xv   = (u==0)?xq.x:(u==1)?xq.y:(u==2)?xq.z:xq.w;

            if (lyr == 0) {
                // ---- L1 step t: gates of units 4q..4q+3 (this lane: u1)
                f32x4 ci;
#pragma unroll
                for (int r = 0; r < 4; ++r)
                    ci[r] = fmaf(wxD[r], xv, cbD[r]);
                const f32x4 d = mfma16(WaA, h1f, ci);
                const float si = sig2(d[0]);
                const float sf = sig2(d[1]);
                const float sg = fmaf(2.f, sig2(d[2]), -1.f);
                const float so = sig2(d[3]);
                c1 = fmaf(sf, c1, si * sg);
                const float th = fmaf(2.f, sig2(NT * c1), -1.f);
                hx[slot][0][n][u1] = (f16)(so * th);
            } else if (t >= 1) {
                // ---- L2 step t-1: gb = Wih1·h1[t-1] + pre2
                const f32x4 d = mfma16(WaA, h1f, pre2);
                const float si = sig2(d[0]);
                const float sf = sig2(d[1]);
                const float sg = fmaf(2.f, sig2(d[2]), -1.f);
                const float so = sig2(d[3]);
                c2 = fmaf(sf, c2, si * sg);
                const float th = fmaf(2.f, sig2(NT * c2), -1.f);
                hx[slot][1][n][u1] = (f16)(so * th);
            }
            __syncthreads();

            // ---- pick up the freshly exchanged h
            h1f = *reinterpret_cast<const f16x4*>(&hx[slot][0][n][4 * Lq]);
            if (lyr == 1 && t >= 1) {
                h2f = *reinterpret_cast<const f16x4*>(&hx[slot][1][n][4 * Lq]);
                pre2 = mfma16(WaB, h2f, cbD);   // for iter t+1 (off-path)
            }
        }
        xq = xn;
    }

    // ---- epilogue: L2 step T-1 (h1f = h1[T-1], pre2 = Whh1·h2[T-2]+b2)
    if (lyr == 1) {
        const f32x4 d = mfma16(WaA, h1f, pre2);
        const float si = sig2(d[0]);
        const float sf = sig2(d[1]);
        const float sg = fmaf(2.f, sig2(d[2]), -1.f);
        const float so = sig2(d[3]);
        c2 = fmaf(sf, c2, si * sg);
        const float th = fmaf(2.f, sig2(NT * c2), -1.f);
        h2fin[n][u1] = so * th;                // f32 for the head
    }
    __syncthreads();

    // ---- head (wave 0): out[seq][m] = relu(h2) . Wout[m] + bout[m]
    if (w8 == 0) {
        const f32x4 hv = *reinterpret_cast<const f32x4*>(&h2fin[n][4 * Lq]);
#pragma unroll
        for (int m5 = 0; m5 < 5; ++m5) {
            float p = 0.f;
#pragma unroll
            for (int r = 0; r < 4; ++r)
                p = fmaf(fmaxf(hv[r], 0.f), Wout[m5 * 16 + 4 * Lq + r], p);
            p += __shfl_xor(p, 16, 64);
            p += __shfl_xor(p, 32, 64);
            if (Lq == 0) out[seq * 5 + m5] = p + bout[m5];
        }
    }
}

extern "C" void kernel_launch(void* const* d_in, const int* in_sizes, int n_in,
                              void* d_out, int out_size, void* d_ws, size_t ws_size,
                              hipStream_t stream) {
    const float* x    = (const float*)d_in[0];
    const float* Wih0 = (const float*)d_in[1];
    const float* Whh0 = (const float*)d_in[2];
    const float* bih0 = (const float*)d_in[3];
    const float* bhh0 = (const float*)d_in[4];
    const float* Wih1 = (const float*)d_in[5];
    const float* Whh1 = (const float*)d_in[6];
    const float* bih1 = (const float*)d_in[7];
    const float* bhh1 = (const float*)d_in[8];
    const float* Wout = (const float*)d_in[9];
    const float* bout = (const float*)d_in[10];
    float* out = (float*)d_out;

    const int B = in_sizes[0] / T_LEN;          // 4096
    dim3 grid(B / 16), block(512);              // 8 waves / 16 seqs per block
    hipLaunchKernelGGL(lstm2_unit_kernel, grid, block, 0, stream,
                       x, Wih0, Whh0, bih0, bhh0,
                       Wih1, Whh1, bih1, bhh1, Wout, bout, out);
}